// Round 1
// baseline (400.666 us; speedup 1.0000x reference)
//
#include <hip/hip_runtime.h>
#include <hip/hip_bf16.h>
#include <cstdint>
#include <cstddef>

typedef __attribute__((ext_vector_type(8))) short short8;
typedef __attribute__((ext_vector_type(4))) float f32x4;
typedef unsigned int u32;
typedef unsigned short u16;

// ---------- helpers ----------
__device__ inline u16 f2b(float x) {
    union { float f; u32 u; } v; v.f = x;
    u32 u = v.u;
    u32 r = (u + 0x7fff + ((u >> 16) & 1)) >> 16;
    return (u16)r;
}
__device__ inline float b2f(u16 h) {
    union { u32 u; float f; } v; v.u = ((u32)h) << 16;
    return v.f;
}

// ---------- weight repack ----------
// Wq/Wk/Wv [H,C,HS] f32 -> WqkvT [3C, C] bf16 where WqkvT[n][c] = W_sel[h][c][d], n = sel*1024 + h*64 + d
__global__ __launch_bounds__(256) void repack_qkv(
    const float* __restrict__ Wq, const float* __restrict__ Wk, const float* __restrict__ Wv,
    u16* __restrict__ out)
{
    int idx = blockIdx.x * 256 + threadIdx.x;      // over 3072*1024
    int n = idx >> 10, c = idx & 1023;
    int sel = n >> 10, hn = n & 1023;
    int h = hn >> 6, d = hn & 63;
    const float* W = (sel == 0) ? Wq : (sel == 1) ? Wk : Wv;
    out[idx] = f2b(W[((size_t)h * 1024 + c) * 64 + d]);
}

// in [P? ...]: out[q*P + p] = in[p*Q + q]; out is [Q, P] bf16, in is [P, Q] f32
__global__ __launch_bounds__(256) void trans_cast(
    const float* __restrict__ in, u16* __restrict__ out, int P, int Q)
{
    int idx = blockIdx.x * 256 + threadIdx.x;
    int q = idx / P, p = idx - q * P;
    out[idx] = f2b(in[(size_t)p * Q + q]);
}

// ---------- layernorm (row = 1024 f32), outputs f32 + bf16 ----------
__global__ __launch_bounds__(256) void ln_kernel(
    const float* __restrict__ x, const float* __restrict__ g, const float* __restrict__ be,
    float* __restrict__ yf, u16* __restrict__ yb)
{
    int row = blockIdx.x;
    const float4 v = reinterpret_cast<const float4*>(x + (size_t)row * 1024)[threadIdx.x];
    float s  = v.x + v.y + v.z + v.w;
    float s2 = v.x * v.x + v.y * v.y + v.z * v.z + v.w * v.w;
    #pragma unroll
    for (int o = 32; o >= 1; o >>= 1) { s += __shfl_xor(s, o); s2 += __shfl_xor(s2, o); }
    __shared__ float red[8];
    int w = threadIdx.x >> 6;
    if ((threadIdx.x & 63) == 0) { red[w] = s; red[4 + w] = s2; }
    __syncthreads();
    s  = red[0] + red[1] + red[2] + red[3];
    s2 = red[4] + red[5] + red[6] + red[7];
    float mu = s * (1.0f / 1024.0f);
    float var = s2 * (1.0f / 1024.0f) - mu * mu;
    float rs = rsqrtf(var + 1e-5f);
    const float4 gg = reinterpret_cast<const float4*>(g)[threadIdx.x];
    const float4 bb = reinterpret_cast<const float4*>(be)[threadIdx.x];
    float4 o;
    o.x = (v.x - mu) * rs * gg.x + bb.x;
    o.y = (v.y - mu) * rs * gg.y + bb.y;
    o.z = (v.z - mu) * rs * gg.z + bb.z;
    o.w = (v.w - mu) * rs * gg.w + bb.w;
    reinterpret_cast<float4*>(yf + (size_t)row * 1024)[threadIdx.x] = o;
    uint2 pk;
    pk.x = (u32)f2b(o.x) | ((u32)f2b(o.y) << 16);
    pk.y = (u32)f2b(o.z) | ((u32)f2b(o.w) << 16);
    reinterpret_cast<uint2*>(yb + (size_t)row * 1024)[threadIdx.x] = pk;
}

// ---------- GEMM: C[M,N] = A[M,K](bf16) * BT[N,K](bf16)^T  (+bias, +relu, +resid) ----------
// 128x128 tile, BK=64, 256 threads = 4 waves, each wave 64x64 (4x4 frags of 16x16x32)
template<bool BIAS, bool RELU, bool RESID, bool OUTB>
__global__ __launch_bounds__(256) void gemm_bt(
    const u16* __restrict__ A, int lda,
    const u16* __restrict__ BT, int ldb,
    void* __restrict__ out, int ldo,
    const float* __restrict__ bias,
    const float* __restrict__ resid,
    int K)
{
    __shared__ __align__(16) char smem[32 * 1024];
    char* As = smem;
    char* Bs = smem + 16384;
    const int tid = threadIdx.x;
    const int lane = tid & 63, w = tid >> 6;
    const int wr = w >> 1, wc = w & 1;
    const int l15 = lane & 15, lq = lane >> 4;
    const int m0 = blockIdx.y * 128, n0 = blockIdx.x * 128;

    f32x4 acc[4][4] = {};

    for (int kt = 0; kt < K; kt += 64) {
        #pragma unroll
        for (int it = 0; it < 4; ++it) {
            int idx = tid + it * 256;
            int row = idx >> 3, cb = (idx & 7) * 16;
            int sw = cb ^ ((row & 7) << 4);
            const char* gA = (const char*)(A + (size_t)(m0 + row) * lda + kt) + cb;
            *reinterpret_cast<float4*>(As + row * 128 + sw) = *reinterpret_cast<const float4*>(gA);
            const char* gB = (const char*)(BT + (size_t)(n0 + row) * ldb + kt) + cb;
            *reinterpret_cast<float4*>(Bs + row * 128 + sw) = *reinterpret_cast<const float4*>(gB);
        }
        __syncthreads();
        #pragma unroll
        for (int kk = 0; kk < 2; ++kk) {
            const int cb = kk * 64 + lq * 16;
            short8 a[4], b[4];
            #pragma unroll
            for (int mi = 0; mi < 4; ++mi) {
                int row = wr * 64 + mi * 16 + l15;
                a[mi] = *reinterpret_cast<const short8*>(As + row * 128 + (cb ^ ((row & 7) << 4)));
            }
            #pragma unroll
            for (int ni = 0; ni < 4; ++ni) {
                int row = wc * 64 + ni * 16 + l15;
                b[ni] = *reinterpret_cast<const short8*>(Bs + row * 128 + (cb ^ ((row & 7) << 4)));
            }
            #pragma unroll
            for (int mi = 0; mi < 4; ++mi)
                #pragma unroll
                for (int ni = 0; ni < 4; ++ni)
                    acc[mi][ni] = __builtin_amdgcn_mfma_f32_16x16x32_bf16(a[mi], b[ni], acc[mi][ni], 0, 0, 0);
        }
        __syncthreads();
    }

    #pragma unroll
    for (int mi = 0; mi < 4; ++mi) {
        #pragma unroll
        for (int ni = 0; ni < 4; ++ni) {
            int col = n0 + wc * 64 + ni * 16 + l15;
            float bv = BIAS ? bias[col] : 0.0f;
            #pragma unroll
            for (int r = 0; r < 4; ++r) {
                int row = m0 + wr * 64 + mi * 16 + lq * 4 + r;
                float v = acc[mi][ni][r] + bv;
                if (RELU) v = v > 0.0f ? v : 0.0f;
                if (RESID) v += resid[(size_t)row * ldo + col];
                if (OUTB) ((u16*)out)[(size_t)row * ldo + col] = f2b(v);
                else      ((float*)out)[(size_t)row * ldo + col] = v;
            }
        }
    }
}

// ---------- flash attention (causal), qkv [B*T, 3072] bf16 -> att [B*T, 1024] bf16 ----------
// grid (T/64, H, B), 256 threads = 4 waves; wave w owns q-rows qt*64 + w*16 .. +15
__global__ __launch_bounds__(256) void attn_kernel(
    const u16* __restrict__ qkv, u16* __restrict__ att)
{
    __shared__ __align__(16) char smem[24 * 1024];
    char* Ks = smem;            // [64 s][64 d] bf16, swizzled
    char* Vs = smem + 8192;     // [64 d][64 s] bf16 (transposed), swizzled
    char* Ps = smem + 16384;    // 4 waves x [16 q][64 s] bf16, swizzled

    const int tid = threadIdx.x, lane = tid & 63, w = tid >> 6;
    const int l15 = lane & 15, lq = lane >> 4;
    const int qt = blockIdx.x, h = blockIdx.y, b = blockIdx.z;
    const int T = 2048;
    const int kcol = 1024 + h * 64, vcol = 2048 + h * 64, qcol = h * 64;
    const size_t base = (size_t)b * T;

    // Q fragments (held for whole block)
    const int qrow = qt * 64 + w * 16 + l15;
    const u16* qp = qkv + (base + qrow) * 3072 + qcol + lq * 8;
    short8 qf0 = *reinterpret_cast<const short8*>(qp);
    short8 qf1 = *reinterpret_cast<const short8*>(qp + 32);

    f32x4 oacc[4] = {};
    float mrow[4], lrow[4];
    #pragma unroll
    for (int r = 0; r < 4; ++r) { mrow[r] = -1e30f; lrow[r] = 0.0f; }

    const float scale = 0.03125f;  // C^-0.5 = 1/32
    char* pb = Ps + w * 2048;

    for (int st = 0; st <= qt; ++st) {
        // stage K (row-major) and V (transposed)
        #pragma unroll
        for (int it = 0; it < 2; ++it) {
            int idx = tid + it * 256;
            int srow = idx >> 3, cb8 = idx & 7;
            const u16* g = qkv + (base + st * 64 + srow) * 3072;
            float4 kd = *reinterpret_cast<const float4*>(g + kcol + cb8 * 8);
            *reinterpret_cast<float4*>(Ks + srow * 128 + ((cb8 * 16) ^ ((srow & 7) << 4))) = kd;
            float4 vd = *reinterpret_cast<const float4*>(g + vcol + cb8 * 8);
            u16 vs[8];
            *reinterpret_cast<float4*>(vs) = vd;
            #pragma unroll
            for (int j = 0; j < 8; ++j) {
                int d = cb8 * 8 + j;
                int sw = (((d & 7) ^ (d >> 3)) << 4);
                *reinterpret_cast<u16*>(Vs + d * 128 + ((srow * 2) ^ sw)) = vs[j];
            }
        }
        __syncthreads();

        // S = Q K^T  (wave's 16 q-rows x 64 s-cols)
        f32x4 sa[4] = {};
        #pragma unroll
        for (int kk = 0; kk < 2; ++kk) {
            const int cb = kk * 64 + lq * 16;
            short8 qf = kk ? qf1 : qf0;
            #pragma unroll
            for (int ct = 0; ct < 4; ++ct) {
                int row = ct * 16 + l15;
                short8 kf = *reinterpret_cast<const short8*>(Ks + row * 128 + (cb ^ ((row & 7) << 4)));
                sa[ct] = __builtin_amdgcn_mfma_f32_16x16x32_bf16(qf, kf, sa[ct], 0, 0, 0);
            }
        }
        // scale + causal mask (only needed on diagonal tile)
        const int qg = qt * 64 + w * 16 + lq * 4;
        #pragma unroll
        for (int ct = 0; ct < 4; ++ct) {
            int sg = st * 64 + ct * 16 + l15;
            #pragma unroll
            for (int r = 0; r < 4; ++r) {
                float v = sa[ct][r] * scale;
                if (st == qt && sg > qg + r) v = -1e30f;
                sa[ct][r] = v;
            }
        }
        // row max across 4 col-frags + 16 lanes
        float newm[4], sf[4];
        #pragma unroll
        for (int r = 0; r < 4; ++r) {
            float mx = fmaxf(fmaxf(sa[0][r], sa[1][r]), fmaxf(sa[2][r], sa[3][r]));
            #pragma unroll
            for (int o = 8; o >= 1; o >>= 1) mx = fmaxf(mx, __shfl_xor(mx, o));
            newm[r] = fmaxf(mrow[r], mx);
            sf[r] = __expf(mrow[r] - newm[r]);
            mrow[r] = newm[r];
        }
        // P = exp(S - m), store bf16 to per-wave LDS, accumulate row sums
        float psum[4] = {0.f, 0.f, 0.f, 0.f};
        #pragma unroll
        for (int ct = 0; ct < 4; ++ct) {
            #pragma unroll
            for (int r = 0; r < 4; ++r) {
                float p = __expf(sa[ct][r] - mrow[r]);
                psum[r] += p;
                int prow = lq * 4 + r;
                int pcb = (ct * 16 + l15) * 2;
                *reinterpret_cast<u16*>(pb + prow * 128 + (pcb ^ ((prow & 7) << 4))) = f2b(p);
            }
        }
        #pragma unroll
        for (int r = 0; r < 4; ++r) {
            float s_ = psum[r];
            #pragma unroll
            for (int o = 8; o >= 1; o >>= 1) s_ += __shfl_xor(s_, o);
            lrow[r] = lrow[r] * sf[r] + s_;
            #pragma unroll
            for (int dt = 0; dt < 4; ++dt) oacc[dt][r] *= sf[r];
        }
        // O += P V   (A-frag from Ps, B-frag from transposed Vs)
        #pragma unroll
        for (int kk = 0; kk < 2; ++kk) {
            const int scb = kk * 64 + lq * 16;
            short8 pf = *reinterpret_cast<const short8*>(pb + l15 * 128 + (scb ^ ((l15 & 7) << 4)));
            #pragma unroll
            for (int dt = 0; dt < 4; ++dt) {
                int d = dt * 16 + l15;
                int sw = (((d & 7) ^ (d >> 3)) << 4);
                short8 vf = *reinterpret_cast<const short8*>(Vs + d * 128 + (scb ^ sw));
                oacc[dt] = __builtin_amdgcn_mfma_f32_16x16x32_bf16(pf, vf, oacc[dt], 0, 0, 0);
            }
        }
        __syncthreads();
    }

    // epilogue: normalize and store bf16 [B*T, 1024]
    const size_t orow = base + qt * 64 + w * 16 + lq * 4;
    #pragma unroll
    for (int dt = 0; dt < 4; ++dt) {
        #pragma unroll
        for (int r = 0; r < 4; ++r) {
            float v = oacc[dt][r] / lrow[r];
            att[(orow + r) * 1024 + h * 64 + dt * 16 + l15] = f2b(v);
        }
    }
}

// ---------- launch ----------
extern "C" void kernel_launch(void* const* d_in, const int* in_sizes, int n_in,
                              void* d_out, int out_size, void* d_ws, size_t ws_size,
                              hipStream_t stream)
{
    const float* x   = (const float*)d_in[0];
    const float* Wq  = (const float*)d_in[1];
    const float* Wk  = (const float*)d_in[2];
    const float* Wv  = (const float*)d_in[3];
    const float* Wp  = (const float*)d_in[4];
    const float* bp  = (const float*)d_in[5];
    const float* W1  = (const float*)d_in[6];
    const float* b1  = (const float*)d_in[7];
    const float* W2  = (const float*)d_in[8];
    const float* b2  = (const float*)d_in[9];
    const float* g1  = (const float*)d_in[10];
    const float* be1 = (const float*)d_in[11];
    const float* g2  = (const float*)d_in[12];
    const float* be2 = (const float*)d_in[13];
    float* out = (float*)d_out;

    char* ws = (char*)d_ws;
    // workspace layout (bytes)
    u16*   wqkvT = (u16*)(ws + 0);                  //  6 MiB [3072,1024]
    u16*   wpT   = (u16*)(ws + 6291456);            //  2 MiB [1024,1024]
    u16*   w1T   = (u16*)(ws + 8388608);            //  8 MiB [4096,1024]
    u16*   w2T   = (u16*)(ws + 16777216);           //  8 MiB [1024,4096]
    float* xlnF  = (float*)(ws + 25165824);         // 16 MiB [4096,1024]
    u16*   xlnB  = (u16*)(ws + 41943040);           //  8 MiB [4096,1024]  (reused as yB)
    u16*   qkv   = (u16*)(ws + 50331648);           // 24 MiB [4096,3072]
    float* x2    = (float*)(ws + 50331648);         // 16 MiB (reuses qkv region after attn)
    u16*   hbuf  = (u16*)(ws + 50331648);           // 32 MiB [4096,4096] (reuses x2+att after ln2/proj)
    u16*   attb  = (u16*)(ws + 75497472);           //  8 MiB [4096,1024]
    float* yF    = (float*)(ws + 83886080);         // 16 MiB [4096,1024]
    u16*   yB    = xlnB;

    // 1. repack weights -> bf16 transposed
    repack_qkv<<<(3072 * 1024) / 256, 256, 0, stream>>>(Wq, Wk, Wv, wqkvT);
    trans_cast<<<(1024 * 1024) / 256, 256, 0, stream>>>(Wp, wpT, 1024, 1024);
    trans_cast<<<(4096 * 1024) / 256, 256, 0, stream>>>(W1, w1T, 1024, 4096);
    trans_cast<<<(4096 * 1024) / 256, 256, 0, stream>>>(W2, w2T, 4096, 1024);

    // 2. LN1
    ln_kernel<<<4096, 256, 0, stream>>>(x, g1, be1, xlnF, xlnB);

    // 3. QKV = xln @ Wqkv  -> bf16 [4096, 3072]
    gemm_bt<false, false, false, true><<<dim3(24, 32), 256, 0, stream>>>(
        xlnB, 1024, wqkvT, 1024, qkv, 3072, nullptr, nullptr, 1024);

    // 4. attention -> att bf16 [4096, 1024]
    attn_kernel<<<dim3(32, 16, 2), 256, 0, stream>>>(qkv, attb);

    // 5. x2 = xln + att @ Wp + bp   (f32)
    gemm_bt<true, false, true, false><<<dim3(8, 32), 256, 0, stream>>>(
        attb, 1024, wpT, 1024, x2, 1024, bp, xlnF, 1024);

    // 6. LN2
    ln_kernel<<<4096, 256, 0, stream>>>(x2, g2, be2, yF, yB);

    // 7. h = relu(y @ W1 + b1) -> bf16 [4096, 4096]
    gemm_bt<true, true, false, true><<<dim3(32, 32), 256, 0, stream>>>(
        yB, 1024, w1T, 1024, hbuf, 4096, b1, nullptr, 1024);

    // 8. out = y + h @ W2 + b2 -> f32 [4096, 1024]
    gemm_bt<true, false, true, false><<<dim3(8, 32), 256, 0, stream>>>(
        hbuf, 4096, w2T, 4096, out, 1024, b2, yF, 4096);
}